// Round 5
// baseline (741.192 us; speedup 1.0000x reference)
//
#include <hip/hip_runtime.h>
#include <hip/hip_cooperative_groups.h>

namespace cg = cooperative_groups;

typedef float __attribute__((ext_vector_type(4))) f32x4;

#define RSTASH 16   // d-slices stashed in registers (f32x4 each -> 64 VGPRs)
#define LSTASH 3    // d-slices stashed in LDS (16 KiB each -> 48 KiB)

// ============================================================================
// Fused cooperative kernel. One block per (n,c) cube, 1 block/CU (256 blocks
// x 1024 threads, <=128 VGPR via launch_bounds, <=64 KiB LDS).
// Phase 1: pool the cube (xd/xh/xw means) while stashing d-slices 0..18
//          on-chip (16 in registers, 3 in LDS). Coalesced float4 reads.
// grid.sync(): pools of all 64 c-blocks of each n become visible.
// Phase 2: t<192 recomputes the tiny gate chain (conv1+BN+hardswish+convX+
//          sigmoid) entirely in registers -> a_s[192] in LDS.
// Phase 3: out = x * a[d]*a[64+h]*a[128+w]; stashed slices come from
//          regs/LDS (30% of x never re-read), rest nt-load; all stores nt
//          (out never re-read; keep x lines in the Infinity Cache).
// Cache-policy A/Bs (rounds 1-4): nt STORE = -20us; load policy & traversal
// order = noise. This round removes re-read bytes instead.
// ============================================================================
__global__ __launch_bounds__(1024, 4) void coord_att_k(
    const float* __restrict__ x,
    const float* __restrict__ w1, const float* __restrict__ b1,
    const float* __restrict__ gam, const float* __restrict__ bet,
    const float* __restrict__ mu,  const float* __restrict__ var,
    const float* __restrict__ wd,  const float* __restrict__ bd,
    const float* __restrict__ wh,  const float* __restrict__ bh,
    const float* __restrict__ ww,  const float* __restrict__ bw,
    float* __restrict__ out, float* __restrict__ pool)
{
    const int blk = blockIdx.x;          // n*64 + c
    const int n = blk >> 6, c = blk & 63;
    const int t  = threadIdx.x;
    const int w4 = t & 15;               // w-quad
    const int h  = t >> 4;               // 0..63

    __shared__ float sd[64], sh[64], sw[64];
    __shared__ float a_s[192];
    __shared__ f32x4 stash[LSTASH * 1024];   // 48 KiB

    if (t < 64) { sd[t] = 0.f; sh[t] = 0.f; sw[t] = 0.f; }
    __syncthreads();

    const f32x4* __restrict__ xp = (const f32x4*)(x + (size_t)blk * 262144);

    // ---- Phase 1: pool + stash ----
    f32x4 xr[RSTASH];                    // statically indexed (no scratch)
    float accw[4] = {0,0,0,0};
    float acch = 0.f;

    auto proc = [&](f32x4 v, int d) {
        accw[0] += v.x; accw[1] += v.y; accw[2] += v.z; accw[3] += v.w;
        float s = (v.x + v.y) + (v.z + v.w);
        acch += s;
        float r = s;                     // wave reduce -> one atomic/wave/d
        r += __shfl_down(r, 32);
        r += __shfl_down(r, 16);
        r += __shfl_down(r, 8);
        r += __shfl_down(r, 4);
        r += __shfl_down(r, 2);
        r += __shfl_down(r, 1);
        if ((t & 63) == 0) atomicAdd(&sd[d], r);
    };

    #pragma unroll
    for (int d = 0; d < RSTASH; ++d) {
        f32x4 v = xp[d * 1024 + t];
        xr[d] = v;
        proc(v, d);
    }
    #pragma unroll
    for (int d = RSTASH; d < RSTASH + LSTASH; ++d) {
        f32x4 v = xp[d * 1024 + t];
        stash[(d - RSTASH) * 1024 + t] = v;
        proc(v, d);
    }
    #pragma unroll 4
    for (int d = RSTASH + LSTASH; d < 64; ++d) {
        f32x4 v = xp[d * 1024 + t];
        proc(v, d);
    }
    atomicAdd(&sh[h], acch);
    #pragma unroll
    for (int j = 0; j < 4; ++j) atomicAdd(&sw[w4 * 4 + j], accw[j]);
    __syncthreads();

    if (t < 192) {
        float v = (t < 64) ? sd[t] : (t < 128) ? sh[t - 64] : sw[t - 128];
        pool[(n * 192 + t) * 64 + c] = v * (1.0f / 4096.0f);
    }

    __threadfence();                     // pool visible device-wide
    cg::this_grid().sync();

    // ---- Phase 2: gates, all-register (stage A and B share the same t) ----
    if (t < 192) {
        float acc[8] = {0,0,0,0,0,0,0,0};
        const f32x4* __restrict__ pp = (const f32x4*)(pool + (n * 192 + t) * 64);
        #pragma unroll 4
        for (int c4 = 0; c4 < 16; ++c4) {
            f32x4 p = pp[c4];
            const int cb = c4 * 4;
            #pragma unroll
            for (int m = 0; m < 8; ++m) {
                acc[m] += p.x * w1[m * 64 + cb]
                        + p.y * w1[m * 64 + cb + 1]
                        + p.z * w1[m * 64 + cb + 2]
                        + p.w * w1[m * 64 + cb + 3];
            }
        }
        const float* wsel; float bsel;
        if (t < 64)       { wsel = wd + c * 8; bsel = bd[c]; }
        else if (t < 128) { wsel = wh + c * 8; bsel = bh[c]; }
        else              { wsel = ww + c * 8; bsel = bw[c]; }
        float vg = bsel;
        #pragma unroll
        for (int m = 0; m < 8; ++m) {
            float scale = gam[m] * rsqrtf(var[m] + 1e-5f);
            float yv = (acc[m] + b1[m] - mu[m]) * scale + bet[m];
            float hs = yv * fminf(fmaxf(yv + 3.0f, 0.0f), 6.0f) * (1.0f / 6.0f);
            vg += hs * wsel[m];
        }
        a_s[t] = 1.0f / (1.0f + __expf(-vg));
    }
    __syncthreads();

    // ---- Phase 3: out = x * ad*ah*aw ----
    f32x4 gw;
    gw.x = a_s[128 + w4 * 4 + 0];
    gw.y = a_s[128 + w4 * 4 + 1];
    gw.z = a_s[128 + w4 * 4 + 2];
    gw.w = a_s[128 + w4 * 4 + 3];
    const float ahr = a_s[64 + h];
    f32x4* __restrict__ op = (f32x4*)(out + (size_t)blk * 262144);

    #pragma unroll
    for (int k = 0; k < RSTASH; ++k) {               // from registers
        const float s = a_s[k] * ahr;
        f32x4 o = xr[k] * (gw * s);
        __builtin_nontemporal_store(o, &op[k * 1024 + t]);
    }
    #pragma unroll
    for (int k = RSTASH; k < RSTASH + LSTASH; ++k) { // from LDS
        const float s = a_s[k] * ahr;
        f32x4 o = stash[(k - RSTASH) * 1024 + t] * (gw * s);
        __builtin_nontemporal_store(o, &op[k * 1024 + t]);
    }
    #pragma unroll 2
    for (int k = RSTASH + LSTASH; k < 64; ++k) {     // re-read remainder
        const float s = a_s[k] * ahr;
        f32x4 v = __builtin_nontemporal_load(&xp[k * 1024 + t]);
        f32x4 o = v * (gw * s);
        __builtin_nontemporal_store(o, &op[k * 1024 + t]);
    }
}

extern "C" void kernel_launch(void* const* d_in, const int* in_sizes, int n_in,
                              void* d_out, int out_size, void* d_ws, size_t ws_size,
                              hipStream_t stream) {
    const float* x   = (const float*)d_in[0];
    const float* w1  = (const float*)d_in[1];
    const float* b1  = (const float*)d_in[2];
    const float* gam = (const float*)d_in[3];
    const float* bet = (const float*)d_in[4];
    const float* mu  = (const float*)d_in[5];
    const float* var = (const float*)d_in[6];
    const float* wd  = (const float*)d_in[7];
    const float* bd  = (const float*)d_in[8];
    const float* wh  = (const float*)d_in[9];
    const float* bh  = (const float*)d_in[10];
    const float* ww  = (const float*)d_in[11];
    const float* bw  = (const float*)d_in[12];
    float* out  = (float*)d_out;
    float* pool = (float*)d_ws;          // 4*192*64 f32 = 192 KiB

    void* args[] = {
        (void*)&x,
        (void*)&w1, (void*)&b1, (void*)&gam, (void*)&bet,
        (void*)&mu, (void*)&var, (void*)&wd, (void*)&bd,
        (void*)&wh, (void*)&bh, (void*)&ww, (void*)&bw,
        (void*)&out, (void*)&pool
    };
    hipLaunchCooperativeKernel((const void*)coord_att_k,
                               dim3(256), dim3(1024), args, 0, stream);
}

// Round 6
// 519.079 us; speedup vs baseline: 1.4279x; 1.4279x over previous
//
#include <hip/hip_runtime.h>

typedef unsigned int uint;
typedef unsigned short ushort;
typedef float __attribute__((ext_vector_type(4))) f32x4;

// ============================================================================
// Kernel 1: per-(n,c) cube (64^3 f32 = 1 MB) -> xd[64], xh[64], xw[64] means.
// 1024 threads = 16 waves. Wave wv owns d-slices {wv, 16+wv, 32+wv, 48+wv}.
// Coalesced float4 reads (1 KiB/wave/instr). Reduction geometry minimizes DS
// ops (measured round 3: DS-op count is NOT the bottleneck, but keep it lean).
// pool layout (f32, in d_ws): [n][l][c]; l: 0..63 = d, 64..127 = h,
// 128..191 = w. Transposed so kernel 2 reads rows with float4.
// ============================================================================
__global__ __launch_bounds__(1024) void pool_k(const float* __restrict__ x,
                                               float* __restrict__ pool) {
    const int blk = blockIdx.x;          // n*64 + c
    const int t  = threadIdx.x;
    const int wv = t >> 6;               // wave 0..15
    const int l  = t & 63;               // lane
    const int g  = l >> 4;               // 0..3  (h-subgroup)
    const int w4 = l & 15;               // w-quad
    __shared__ float sd[64], sh[64], sw[64];
    if (t < 64) { sh[t] = 0.f; sw[t] = 0.f; }
    __syncthreads();

    const float4* __restrict__ xp = (const float4*)(x + (size_t)blk * 262144);
    const float4* __restrict__ base = xp + wv * 1024 + l;

    float accd[4] = {0,0,0,0};           // per owned d-slice
    float accw[4] = {0,0,0,0};           // per w-in-quad component

    #pragma unroll 4
    for (int j = 0; j < 16; ++j) {       // h-row-quad within slice
        float acch = 0.f;
        #pragma unroll
        for (int k = 0; k < 4; ++k) {    // which owned slice (d = k*16+wv)
            float4 v = base[k * 16384 + j * 64];
            accw[0] += v.x; accw[1] += v.y; accw[2] += v.z; accw[3] += v.w;
            float s = (v.x + v.y) + (v.z + v.w);
            accd[k] += s;
            acch += s;
        }
        // reduce over the 16-lane w4 subgroup (h = j*4 + g is uniform there)
        acch += __shfl_xor(acch, 1);
        acch += __shfl_xor(acch, 2);
        acch += __shfl_xor(acch, 4);
        acch += __shfl_xor(acch, 8);
        if (w4 == 0) atomicAdd(&sh[j * 4 + g], acch);
    }

    // sd: full-wave reduce, one per owned slice; store is wave-exclusive.
    #pragma unroll
    for (int k = 0; k < 4; ++k) {
        float r = accd[k];
        r += __shfl_down(r, 32);
        r += __shfl_down(r, 16);
        r += __shfl_down(r, 8);
        r += __shfl_down(r, 4);
        r += __shfl_down(r, 2);
        r += __shfl_down(r, 1);
        if (l == 0) sd[k * 16 + wv] = r;
    }

    // sw: combine the 4 g-subgroups (same w4), then one atomic per w.
    #pragma unroll
    for (int jj = 0; jj < 4; ++jj) {
        float r = accw[jj];
        r += __shfl_down(r, 32);
        r += __shfl_down(r, 16);
        if (l < 16) atomicAdd(&sw[l * 4 + jj], r);
    }
    __syncthreads();

    if (t < 192) {
        float v = (t < 64) ? sd[t] : (t < 128) ? sh[t - 64] : sw[t - 128];
        const int n = blk >> 6, c = blk & 63;
        pool[(n * 192 + t) * 64 + c] = v * (1.0f / 4096.0f);
    }
}

// ============================================================================
// Kernel 2: per-(n,c) block. Stage A/B: tiny gate chain -> a_s[192] in LDS.
// Stage C: out = x * a[d] * a[64+h] * a[128+w], nt load + nt store
// (A/B-settled rounds 1-4: nt STORE = -20us; load policy/traversal = noise).
// Round-6 changes, both att_k-only:
//  (1) T14 async split: the first 8 slice-loads are ISSUED BEFORE stage A so
//      the gate-chain latency (exposed at 1 block/CU) hides the HBM latency.
//  (2) Stage C is batched 8-loads-then-8-stores (128 B/lane per direction)
//      to cut HBM read<->write bus turnarounds 8x vs per-iter alternation.
// ============================================================================
__global__ __launch_bounds__(1024) void att_k(
    const float* __restrict__ x, const float* __restrict__ pool,
    const float* __restrict__ w1, const float* __restrict__ b1,
    const float* __restrict__ gam, const float* __restrict__ bet,
    const float* __restrict__ mu,  const float* __restrict__ var,
    const float* __restrict__ wd,  const float* __restrict__ bd,
    const float* __restrict__ wh,  const float* __restrict__ bh,
    const float* __restrict__ ww,  const float* __restrict__ bw,
    float* __restrict__ out)
{
    const int blk = blockIdx.x;
    const int n = blk >> 6, c = blk & 63;
    const int t = threadIdx.x;
    __shared__ float y_s[8][192];
    __shared__ float a_s[192];

    const f32x4* __restrict__ xp = (const f32x4*)(x   + (size_t)blk * 262144);
    f32x4*       __restrict__ op = (f32x4*)      (out + (size_t)blk * 262144);

    // ---- Prefetch slices 0..7 BEFORE the gate chain (T14 async split) ----
    f32x4 pf[8];
    #pragma unroll
    for (int k = 0; k < 8; ++k)
        pf[k] = __builtin_nontemporal_load(&xp[k * 1024 + t]);

    // ---- Stage A: y[m][l] = hardswish(BN(conv1(pool))) ----
    if (t < 192) {
        float acc[8] = {0,0,0,0,0,0,0,0};
        const f32x4* __restrict__ pp = (const f32x4*)(pool + (n * 192 + t) * 64);
        #pragma unroll 4
        for (int c4 = 0; c4 < 16; ++c4) {
            f32x4 p = pp[c4];
            const int cb = c4 * 4;
            #pragma unroll
            for (int m = 0; m < 8; ++m) {
                acc[m] += p.x * w1[m * 64 + cb]
                        + p.y * w1[m * 64 + cb + 1]
                        + p.z * w1[m * 64 + cb + 2]
                        + p.w * w1[m * 64 + cb + 3];
            }
        }
        #pragma unroll
        for (int m = 0; m < 8; ++m) {
            float scale = gam[m] * rsqrtf(var[m] + 1e-5f);
            float v = (acc[m] + b1[m] - mu[m]) * scale + bet[m];
            float hs = v * fminf(fmaxf(v + 3.0f, 0.0f), 6.0f) * (1.0f / 6.0f);
            y_s[m][t] = hs;
        }
    }
    __syncthreads();

    // ---- Stage B: gates a[l] = sigmoid(conv{d,h,w}(y)[o=c]) ----
    if (t < 192) {
        const float* wsel; float bsel;
        if (t < 64)       { wsel = wd + c * 8; bsel = bd[c]; }
        else if (t < 128) { wsel = wh + c * 8; bsel = bh[c]; }
        else              { wsel = ww + c * 8; bsel = bw[c]; }
        float v = bsel;
        #pragma unroll
        for (int m = 0; m < 8; ++m) v += y_s[m][t] * wsel[m];
        a_s[t] = 1.0f / (1.0f + __expf(-v));
    }
    __syncthreads();

    // ---- Stage C: out = x * ad*ah*aw, batched 8-load/8-store groups ----
    const int w4 = t & 15;
    const int h  = t >> 4;
    f32x4 gw;
    gw.x = a_s[128 + w4 * 4 + 0];
    gw.y = a_s[128 + w4 * 4 + 1];
    gw.z = a_s[128 + w4 * 4 + 2];
    gw.w = a_s[128 + w4 * 4 + 3];
    const float ahr = a_s[64 + h];

    // drain the prefetched batch first (loads were in flight through A/B)
    #pragma unroll
    for (int k = 0; k < 8; ++k) {
        const float s = a_s[k] * ahr;
        __builtin_nontemporal_store(pf[k] * (gw * s), &op[k * 1024 + t]);
    }
    // remaining 56 slices: 8 loads, then 8 gated stores, per group
    for (int kb = 8; kb < 64; kb += 8) {
        f32x4 v[8];
        #pragma unroll
        for (int j = 0; j < 8; ++j)
            v[j] = __builtin_nontemporal_load(&xp[(kb + j) * 1024 + t]);
        #pragma unroll
        for (int j = 0; j < 8; ++j) {
            const float s = a_s[kb + j] * ahr;
            __builtin_nontemporal_store(v[j] * (gw * s), &op[(kb + j) * 1024 + t]);
        }
    }
}

extern "C" void kernel_launch(void* const* d_in, const int* in_sizes, int n_in,
                              void* d_out, int out_size, void* d_ws, size_t ws_size,
                              hipStream_t stream) {
    const float* x = (const float*)d_in[0];
    float* pool = (float*)d_ws;   // 4*192*64 f32 = 192 KiB

    pool_k<<<256, 1024, 0, stream>>>(x, pool);
    att_k<<<256, 1024, 0, stream>>>(x, pool,
        (const float*)d_in[1],  (const float*)d_in[2],
        (const float*)d_in[3],  (const float*)d_in[4],
        (const float*)d_in[5],  (const float*)d_in[6],
        (const float*)d_in[7],  (const float*)d_in[8],
        (const float*)d_in[9],  (const float*)d_in[10],
        (const float*)d_in[11], (const float*)d_in[12],
        (float*)d_out);
}